// Round 3
// baseline (187.986 us; speedup 1.0000x reference)
//
#include <hip/hip_runtime.h>
#include <math.h>

#define FMPX 40
#define NPOS 1600          // 40*40
#define NCLS 80
#define NBOX 8000
#define KDIM 512
#define CAP  256           // per-class candidate capacity (expected ~100/class, >12 sigma)

// anchor (w,h) pairs
__constant__ float c_aw[5] = {17.f, 55.f, 92.f, 202.f, 289.f};
__constant__ float c_ah[5] = {25.f, 75.f, 206.f, 21.f, 311.f};

__device__ __forceinline__ float sigf(float x) { return 1.0f / (1.0f + expf(-x)); }

// ---------------------------------------------------------------------------
// K1: the three 1x1-conv GEMMs. BYTE-IDENTICAL to the R5-verified kernel.
// (R6/R6b added cross-kernel counter zeroing here; both runs died at the
// container level. Reverted to the proven binary to isolate the k_nms change.)
// R3 lesson: with both A and W in LDS the kernel is LDS-pipe-bound.
// R4 lesson: per-step s_load W is worse (OOO SMEM forces lgkmcnt(0)).
// R5: A straight from GLOBAL (L2-resident 3.3MB < 4MB/XCD), software-
// pipelined two 8-k register buffers deep. W staged once into LDS.
// NO barriers in the K-loop. Per-acc FMA order strictly sequential ascending
// k — bitwise-identical across rounds (absmax stable at 2.0).
// ---------------------------------------------------------------------------
__global__ __launch_bounds__(256) void k_gemm(
    const float* __restrict__ cls_feat, const float* __restrict__ reg_feat,
    const float* __restrict__ w_obj, const float* __restrict__ b_obj,
    const float* __restrict__ w_cls, const float* __restrict__ b_cls,
    const float* __restrict__ w_reg, const float* __restrict__ b_reg,
    float* __restrict__ clsRaw,   // [1600][400]
    float* __restrict__ roRaw)    // [1600][25]: 0..4 obj, 5..24 reg
{
    __shared__ float Ws[16 * KDIM];        // 32 KB
    const int mTile = blockIdx.x;          // 0..24
    const int nTile = blockIdx.y;          // 0..26
    const int hw0   = mTile * 64;
    const bool isCls = (nTile < 25);
    const float* feat = isCls ? cls_feat : reg_feat;

    const int pos = threadIdx.x & 63;
    const int og  = threadIdx.x >> 6;      // 0..3 (wave-uniform by construction)

    // A pointer for this lane's position; k strides by NPOS floats.
    const float* ap = feat + hw0 + pos;

    // Initial A prefetch (k=0..15) — independent of W staging, issue early.
    float A0[8], A1[8];
#pragma unroll
    for (int t = 0; t < 8; t++) A0[t] = ap[t * NPOS];
#pragma unroll
    for (int t = 0; t < 8; t++) A1[t] = ap[(8 + t) * NPOS];

    // ---- stage W tile [16][512] (coalesced float4; 8 iters/thread) ----
    for (int i = threadIdx.x * 4; i < 16 * KDIM; i += 256 * 4) {
        int r = i >> 9, k = i & 511;
        const float* src;
        bool valid = true;
        if (isCls) {
            src = w_cls + (nTile * 16 + r) * KDIM + k;
        } else {
            int o = (nTile - 25) * 16 + r;
            if (o < 5)       src = w_obj + o * KDIM + k;
            else if (o < 25) src = w_reg + (o - 5) * KDIM + k;
            else           { src = w_obj; valid = false; }
        }
        float4 v = valid ? *(const float4*)src : make_float4(0.f, 0.f, 0.f, 0.f);
        *(float4*)&Ws[i] = v;
    }

    // ---- per-thread output metadata (wave-uniform) ----
    float bias[4];
    bool ok[4];
#pragma unroll
    for (int j = 0; j < 4; j++) {
        int r = og * 4 + j;                // row within the 16-wide tile
        if (isCls) {
            bias[j] = b_cls[nTile * 16 + r]; ok[j] = true;
        } else {
            int o = (nTile - 25) * 16 + r;
            if (o < 5)       { bias[j] = b_obj[o];     ok[j] = true; }
            else if (o < 25) { bias[j] = b_reg[o - 5]; ok[j] = true; }
            else             { bias[j] = 0.0f;         ok[j] = false; }
        }
    }

    __syncthreads();   // Ws ready; only barrier in the kernel

    float acc[4] = {0.f, 0.f, 0.f, 0.f};
    const float* wsBase = &Ws[(og * 4) * KDIM];

    // Main loop: pairs of 8-k steps; prefetch 16 k ahead. kk = 0..480.
    for (int kk = 0; kk < KDIM - 16; kk += 16) {
        // consume A0 (k = kk..kk+7)
#pragma unroll
        for (int j = 0; j < 4; j++) {
            const float* wp = wsBase + j * KDIM + kk;    // LDS b128 x2, broadcast
            acc[j] += A0[0] * wp[0]; acc[j] += A0[1] * wp[1];
            acc[j] += A0[2] * wp[2]; acc[j] += A0[3] * wp[3];
            acc[j] += A0[4] * wp[4]; acc[j] += A0[5] * wp[5];
            acc[j] += A0[6] * wp[6]; acc[j] += A0[7] * wp[7];
        }
#pragma unroll
        for (int t = 0; t < 8; t++) A0[t] = ap[(kk + 16 + t) * NPOS];
        // consume A1 (k = kk+8..kk+15)
#pragma unroll
        for (int j = 0; j < 4; j++) {
            const float* wp = wsBase + j * KDIM + kk + 8;
            acc[j] += A1[0] * wp[0]; acc[j] += A1[1] * wp[1];
            acc[j] += A1[2] * wp[2]; acc[j] += A1[3] * wp[3];
            acc[j] += A1[4] * wp[4]; acc[j] += A1[5] * wp[5];
            acc[j] += A1[6] * wp[6]; acc[j] += A1[7] * wp[7];
        }
#pragma unroll
        for (int t = 0; t < 8; t++) A1[t] = ap[(kk + 24 + t) * NPOS];
    }
    // tail: k = 496..511, no prefetch
    {
        const int kk = KDIM - 16;
#pragma unroll
        for (int j = 0; j < 4; j++) {
            const float* wp = wsBase + j * KDIM + kk;
            acc[j] += A0[0] * wp[0]; acc[j] += A0[1] * wp[1];
            acc[j] += A0[2] * wp[2]; acc[j] += A0[3] * wp[3];
            acc[j] += A0[4] * wp[4]; acc[j] += A0[5] * wp[5];
            acc[j] += A0[6] * wp[6]; acc[j] += A0[7] * wp[7];
        }
#pragma unroll
        for (int j = 0; j < 4; j++) {
            const float* wp = wsBase + j * KDIM + kk + 8;
            acc[j] += A1[0] * wp[0]; acc[j] += A1[1] * wp[1];
            acc[j] += A1[2] * wp[2]; acc[j] += A1[3] * wp[3];
            acc[j] += A1[4] * wp[4]; acc[j] += A1[5] * wp[5];
            acc[j] += A1[6] * wp[6]; acc[j] += A1[7] * wp[7];
        }
    }

    const int hw = hw0 + pos;
    if (isCls) {
        float4 rv = make_float4(acc[0] + bias[0], acc[1] + bias[1],
                                acc[2] + bias[2], acc[3] + bias[3]);
        *(float4*)&clsRaw[hw * 400 + nTile * 16 + og * 4] = rv;
    } else {
#pragma unroll
        for (int j = 0; j < 4; j++) {
            int o = (nTile - 25) * 16 + og * 4 + j;
            if (ok[j]) roRaw[hw * 25 + o] = acc[j] + bias[j];
        }
    }
}

// ---------------------------------------------------------------------------
// K2: per-box scores, argmax label, decode, outputs. BYTE-IDENTICAL to the
// R5-verified kernel (the R6 bucket-scatter variant is suspect in the
// container deaths and is reverted).
// ---------------------------------------------------------------------------
__global__ __launch_bounds__(256) void k_box(
    const float* __restrict__ clsRaw, const float* __restrict__ roRaw,
    float* __restrict__ out,          // d_out: [32000 bboxes][8000 score][8000 labels][8000 keep]
    float4* __restrict__ nmsBox, float* __restrict__ nmsArea,
    float2* __restrict__ sl)          // packed (score,label) for k_nms scan
{
    const int n = blockIdx.x * 4 + (threadIdx.x >> 6);   // box index 0..7999
    const int lane = threadIdx.x & 63;
    const int hw = n / 5, a = n % 5;

    const float sobj = sigf(roRaw[hw * 25 + a]);
    const float* cbase = clsRaw + hw * 400 + a * 80;

    const int l4 = (lane < 20) ? lane : 19;     // clamp for safe address
    float4 cs = *(const float4*)(cbase + l4 * 4);

    // in-lane first-max over classes l4*4 .. l4*4+3 (strict > keeps first)
    float s0 = sqrtf(sobj * sigf(cs.x));
    float s1 = sqrtf(sobj * sigf(cs.y));
    float s2 = sqrtf(sobj * sigf(cs.z));
    float s3 = sqrtf(sobj * sigf(cs.w));
    float v = s0; int bi = l4 * 4;
    if (s1 > v) { v = s1; bi = l4 * 4 + 1; }
    if (s2 > v) { v = s2; bi = l4 * 4 + 2; }
    if (s3 > v) { v = s3; bi = l4 * 4 + 3; }
    if (lane >= 20) { v = -1.0f; bi = 0x7FFFFFFF; }  // scores are always > 0

    // cross-lane: max score, ties -> lowest class
#pragma unroll
    for (int off = 32; off >= 1; off >>= 1) {
        float ov = __shfl_xor(v, off);
        int   oi = __shfl_xor(bi, off);
        if (ov > v || (ov == v && oi < bi)) { v = ov; bi = oi; }
    }

    if (lane == 0) {
        const float* rp = roRaw + hw * 25 + 5 + a * 4;
        float r0 = rp[0], r1 = rp[1], r2 = rp[2], r3 = rp[3];
        float gx = (float)(hw % FMPX), gy = (float)(hw / FMPX);
        float cx = (sigf(r0) + gx) * 32.0f;
        float cy = (sigf(r1) + gy) * 32.0f;
        float wv = expf(r2) * c_aw[a];
        float hv = expf(r3) * c_ah[a];
        float x1 = cx - wv * 0.5f, y1 = cy - hv * 0.5f;
        float x2 = cx + wv * 0.5f, y2 = cy + hv * 0.5f;

        out[n * 4 + 0] = x1; out[n * 4 + 1] = y1;
        out[n * 4 + 2] = x2; out[n * 4 + 3] = y2;
        out[32000 + n] = v;
        out[40000 + n] = (float)bi;
        out[48000 + n] = 0.0f;            // keep init (k_nms sets 1s later)
        sl[n] = make_float2(v, (float)bi);

        // b2: reinterpret x1y1x2y2 as cxcywh (faithful to the reference nms())
        float nx1 = x1 - x2 * 0.5f, ny1 = y1 - y2 * 0.5f;
        float nx2 = x1 + x2 * 0.5f, ny2 = y1 + y2 * 0.5f;
        nmsBox[n]  = make_float4(nx1, ny1, nx2, ny2);
        nmsArea[n] = (nx2 - nx1) * (ny2 - ny1);
    }
}

// ---------------------------------------------------------------------------
// K3 (R7): same grid/args/inputs as R5 (80 blocks x 256 thr; sl, nmsBox,
// nmsArea). Phase 1 (scan + LDS-atomic compaction) is verbatim R5. What
// changed: the 36-pass LDS bitonic sort and the m-iteration barrier+LDS
// greedy loop (the two serial latency chains that made R5's k_nms 41 us at
// 1.7% VALUBusy) are replaced by a wave-synchronous register greedy on wave 0:
//   - <=CAP candidates live in registers (4 per lane of one 64-lane wave)
//   - per iteration: 6-step shfl_xor argmax over (score desc, idx asc) ==
//     the next element of the stable sorted order among active candidates
//     (so keeps are identical to sort-then-scan greedy); broadcast winner's
//     box; all lanes suppress their candidates in-register.
//   - zero barriers / LDS / memory in the loop; iterations = #kept boxes.
// Compaction order nondeterminism is irrelevant: argmax selection is
// order-independent (CAP=256 never hit at ~100 expected candidates/class).
// IoU expression and operand order identical to R5 -> identical keep set.
// ---------------------------------------------------------------------------
__global__ __launch_bounds__(256) void k_nms(
    const float2* __restrict__ sl,
    const float4* __restrict__ nmsBox, const float* __restrict__ nmsArea,
    float* __restrict__ keepOut)
{
    const int c = blockIdx.x;

    __shared__ float ss[CAP];
    __shared__ int   si[CAP];
    __shared__ int   cnt;

    if (threadIdx.x == 0) cnt = 0;
    __syncthreads();

    for (int i = threadIdx.x; i < NBOX; i += 256) {
        float2 p = sl[i];
        if (p.x >= 0.3f && (int)p.y == c) {
            int q = atomicAdd(&cnt, 1);          // LDS atomic
            if (q < CAP) { ss[q] = p.x; si[q] = i; }
        }
    }
    __syncthreads();

    if (threadIdx.x >= 64) return;               // wave 0 finishes alone
    const int lane = threadIdx.x;
    int m = cnt;
    if (m > CAP) m = CAP;                        // overflow drop == R5 semantics

    // ---- load candidates into registers: 4 per lane ----
    float s[4]; int id[4];
    float x1[4], y1[4], x2[4], y2[4], ar[4];
#pragma unroll
    for (int r = 0; r < 4; r++) {
        int t = r * 64 + lane;
        if (t < m) {
            s[r] = ss[t]; id[r] = si[t];
            float4 b = nmsBox[id[r]];            // gathered, L2-resident
            x1[r] = b.x; y1[r] = b.y; x2[r] = b.z; y2[r] = b.w;
            ar[r] = nmsArea[id[r]];
        } else {
            s[r] = -INFINITY; id[r] = 0x7FFFFFFF;
            x1[r] = 0.f; y1[r] = 0.f; x2[r] = 0.f; y2[r] = 0.f; ar[r] = 0.f;
        }
    }

    // ---- wave-synchronous greedy: each iteration keeps exactly one box ----
    for (int it = 0; it < m; it++) {
        // in-lane best of 4 (score desc, idx asc)
        float bs = s[0]; int bi = id[0]; int bc = 0;
#pragma unroll
        for (int r = 1; r < 4; r++) {
            if (s[r] > bs || (s[r] == bs && id[r] < bi)) { bs = s[r]; bi = id[r]; bc = r; }
        }
        bc |= (lane << 2);                       // code = lane*4 + reg
        // wave butterfly argmax
#pragma unroll
        for (int off = 32; off >= 1; off >>= 1) {
            float os = __shfl_xor(bs, off);
            int   oi = __shfl_xor(bi, off);
            int   oc = __shfl_xor(bc, off);
            if (os > bs || (os == bs && oi < bi)) { bs = os; bi = oi; bc = oc; }
        }
        if (bs == -INFINITY) break;              // nothing active remains

        const int wl = bc >> 2, wr = bc & 3;     // wave-uniform winner location
        // uniform register select, then broadcast winner's box from its lane
        float tx1 = (wr == 0) ? x1[0] : (wr == 1) ? x1[1] : (wr == 2) ? x1[2] : x1[3];
        float ty1 = (wr == 0) ? y1[0] : (wr == 1) ? y1[1] : (wr == 2) ? y1[2] : y1[3];
        float tx2 = (wr == 0) ? x2[0] : (wr == 1) ? x2[1] : (wr == 2) ? x2[2] : x2[3];
        float ty2 = (wr == 0) ? y2[0] : (wr == 1) ? y2[1] : (wr == 2) ? y2[2] : y2[3];
        float tar = (wr == 0) ? ar[0] : (wr == 1) ? ar[1] : (wr == 2) ? ar[2] : ar[3];
        const float kx1 = __shfl(tx1, wl);
        const float ky1 = __shfl(ty1, wl);
        const float kx2 = __shfl(tx2, wl);
        const float ky2 = __shfl(ty2, wl);
        const float ka  = __shfl(tar, wl);

        if (lane == wl) {                        // winner: keep + retire
            keepOut[bi] = 1.0f;
            if      (wr == 0) s[0] = -INFINITY;
            else if (wr == 1) s[1] = -INFINITY;
            else if (wr == 2) s[2] = -INFINITY;
            else              s[3] = -INFINITY;
        }

        // suppress: every still-active candidate vs winner. All active
        // candidates are strictly later in stable (-score, idx) order than
        // the winner (else they'd have won), so this == reference greedy.
#pragma unroll
        for (int r = 0; r < 4; r++) {
            if (s[r] != -INFINITY) {
                float xx1 = fmaxf(kx1, x1[r]);
                float yy1 = fmaxf(ky1, y1[r]);
                float xx2 = fminf(kx2, x2[r]);
                float yy2 = fminf(ky2, y2[r]);
                float inter = fmaxf(1e-10f, xx2 - xx1) * fmaxf(1e-10f, yy2 - yy1);
                float iou = inter / ((ka + ar[r] - inter) + 1e-14f);
                if (iou > 0.5f) s[r] = -INFINITY;
            }
        }
    }
}

// ---------------------------------------------------------------------------
extern "C" void kernel_launch(void* const* d_in, const int* in_sizes, int n_in,
                              void* d_out, int out_size, void* d_ws, size_t ws_size,
                              hipStream_t stream) {
    const float* cls_feat = (const float*)d_in[0];
    const float* reg_feat = (const float*)d_in[1];
    const float* w_obj    = (const float*)d_in[2];
    const float* b_obj    = (const float*)d_in[3];
    const float* w_cls    = (const float*)d_in[4];
    const float* b_cls    = (const float*)d_in[5];
    const float* w_reg    = (const float*)d_in[6];
    const float* b_reg    = (const float*)d_in[7];

    float* out = (float*)d_out;
    float* ws  = (float*)d_ws;

    // workspace layout (floats) — IDENTICAL to the R5-proven layout, 2.944 MB
    float*  clsRaw    = ws;                       // 640000
    float*  roRaw     = ws + 640000;              // 40000
    float4* nmsBox    = (float4*)(ws + 680000);   // 32000 floats (16B-aligned offset)
    float*  nmsArea   = ws + 712000;              // 8000
    float2* sl        = (float2*)(ws + 720000);   // 16000 floats (8B-aligned)
    // total 736000 floats

    k_gemm<<<dim3(25, 27), 256, 0, stream>>>(cls_feat, reg_feat,
                                             w_obj, b_obj, w_cls, b_cls, w_reg, b_reg,
                                             clsRaw, roRaw);
    k_box<<<NBOX / 4, 256, 0, stream>>>(clsRaw, roRaw, out, nmsBox, nmsArea, sl);
    k_nms<<<NCLS, 256, 0, stream>>>(sl, nmsBox, nmsArea, out + 48000);
}

// Round 4
// 162.743 us; speedup vs baseline: 1.1551x; 1.1551x over previous
//
#include <hip/hip_runtime.h>
#include <math.h>

#define FMPX 40
#define NPOS 1600          // 40*40
#define NCLS 80
#define NBOX 8000
#define KDIM 512
#define CAP  256           // per-class candidate capacity (expected ~100/class, >12 sigma)

// anchor (w,h) pairs
__constant__ float c_aw[5] = {17.f, 55.f, 92.f, 202.f, 289.f};
__constant__ float c_ah[5] = {25.f, 75.f, 206.f, 21.f, 311.f};

__device__ __forceinline__ float sigf(float x) { return 1.0f / (1.0f + expf(-x)); }

// ---------------------------------------------------------------------------
// K1: the three 1x1-conv GEMMs. BYTE-IDENTICAL to the R5/R7-verified kernel.
// R3 lesson: with both A and W in LDS the kernel is LDS-pipe-bound.
// R4 lesson: per-step s_load W is worse (OOO SMEM forces lgkmcnt(0)).
// R5: A straight from GLOBAL (L2-resident 3.3MB < 4MB/XCD), software-
// pipelined two 8-k register buffers deep. W staged once into LDS.
// NO barriers in the K-loop. Per-acc FMA order strictly sequential ascending
// k — bitwise-identical across rounds (absmax stable at 2.0).
// ---------------------------------------------------------------------------
__global__ __launch_bounds__(256) void k_gemm(
    const float* __restrict__ cls_feat, const float* __restrict__ reg_feat,
    const float* __restrict__ w_obj, const float* __restrict__ b_obj,
    const float* __restrict__ w_cls, const float* __restrict__ b_cls,
    const float* __restrict__ w_reg, const float* __restrict__ b_reg,
    float* __restrict__ clsRaw,   // [1600][400]
    float* __restrict__ roRaw)    // [1600][25]: 0..4 obj, 5..24 reg
{
    __shared__ float Ws[16 * KDIM];        // 32 KB
    const int mTile = blockIdx.x;          // 0..24
    const int nTile = blockIdx.y;          // 0..26
    const int hw0   = mTile * 64;
    const bool isCls = (nTile < 25);
    const float* feat = isCls ? cls_feat : reg_feat;

    const int pos = threadIdx.x & 63;
    const int og  = threadIdx.x >> 6;      // 0..3 (wave-uniform by construction)

    // A pointer for this lane's position; k strides by NPOS floats.
    const float* ap = feat + hw0 + pos;

    // Initial A prefetch (k=0..15) — independent of W staging, issue early.
    float A0[8], A1[8];
#pragma unroll
    for (int t = 0; t < 8; t++) A0[t] = ap[t * NPOS];
#pragma unroll
    for (int t = 0; t < 8; t++) A1[t] = ap[(8 + t) * NPOS];

    // ---- stage W tile [16][512] (coalesced float4; 8 iters/thread) ----
    for (int i = threadIdx.x * 4; i < 16 * KDIM; i += 256 * 4) {
        int r = i >> 9, k = i & 511;
        const float* src;
        bool valid = true;
        if (isCls) {
            src = w_cls + (nTile * 16 + r) * KDIM + k;
        } else {
            int o = (nTile - 25) * 16 + r;
            if (o < 5)       src = w_obj + o * KDIM + k;
            else if (o < 25) src = w_reg + (o - 5) * KDIM + k;
            else           { src = w_obj; valid = false; }
        }
        float4 v = valid ? *(const float4*)src : make_float4(0.f, 0.f, 0.f, 0.f);
        *(float4*)&Ws[i] = v;
    }

    // ---- per-thread output metadata (wave-uniform) ----
    float bias[4];
    bool ok[4];
#pragma unroll
    for (int j = 0; j < 4; j++) {
        int r = og * 4 + j;                // row within the 16-wide tile
        if (isCls) {
            bias[j] = b_cls[nTile * 16 + r]; ok[j] = true;
        } else {
            int o = (nTile - 25) * 16 + r;
            if (o < 5)       { bias[j] = b_obj[o];     ok[j] = true; }
            else if (o < 25) { bias[j] = b_reg[o - 5]; ok[j] = true; }
            else             { bias[j] = 0.0f;         ok[j] = false; }
        }
    }

    __syncthreads();   // Ws ready; only barrier in the kernel

    float acc[4] = {0.f, 0.f, 0.f, 0.f};
    const float* wsBase = &Ws[(og * 4) * KDIM];

    // Main loop: pairs of 8-k steps; prefetch 16 k ahead. kk = 0..480.
    for (int kk = 0; kk < KDIM - 16; kk += 16) {
        // consume A0 (k = kk..kk+7)
#pragma unroll
        for (int j = 0; j < 4; j++) {
            const float* wp = wsBase + j * KDIM + kk;    // LDS b128 x2, broadcast
            acc[j] += A0[0] * wp[0]; acc[j] += A0[1] * wp[1];
            acc[j] += A0[2] * wp[2]; acc[j] += A0[3] * wp[3];
            acc[j] += A0[4] * wp[4]; acc[j] += A0[5] * wp[5];
            acc[j] += A0[6] * wp[6]; acc[j] += A0[7] * wp[7];
        }
#pragma unroll
        for (int t = 0; t < 8; t++) A0[t] = ap[(kk + 16 + t) * NPOS];
        // consume A1 (k = kk+8..kk+15)
#pragma unroll
        for (int j = 0; j < 4; j++) {
            const float* wp = wsBase + j * KDIM + kk + 8;
            acc[j] += A1[0] * wp[0]; acc[j] += A1[1] * wp[1];
            acc[j] += A1[2] * wp[2]; acc[j] += A1[3] * wp[3];
            acc[j] += A1[4] * wp[4]; acc[j] += A1[5] * wp[5];
            acc[j] += A1[6] * wp[6]; acc[j] += A1[7] * wp[7];
        }
#pragma unroll
        for (int t = 0; t < 8; t++) A1[t] = ap[(kk + 24 + t) * NPOS];
    }
    // tail: k = 496..511, no prefetch
    {
        const int kk = KDIM - 16;
#pragma unroll
        for (int j = 0; j < 4; j++) {
            const float* wp = wsBase + j * KDIM + kk;
            acc[j] += A0[0] * wp[0]; acc[j] += A0[1] * wp[1];
            acc[j] += A0[2] * wp[2]; acc[j] += A0[3] * wp[3];
            acc[j] += A0[4] * wp[4]; acc[j] += A0[5] * wp[5];
            acc[j] += A0[6] * wp[6]; acc[j] += A0[7] * wp[7];
        }
#pragma unroll
        for (int j = 0; j < 4; j++) {
            const float* wp = wsBase + j * KDIM + kk + 8;
            acc[j] += A1[0] * wp[0]; acc[j] += A1[1] * wp[1];
            acc[j] += A1[2] * wp[2]; acc[j] += A1[3] * wp[3];
            acc[j] += A1[4] * wp[4]; acc[j] += A1[5] * wp[5];
            acc[j] += A1[6] * wp[6]; acc[j] += A1[7] * wp[7];
        }
    }

    const int hw = hw0 + pos;
    if (isCls) {
        float4 rv = make_float4(acc[0] + bias[0], acc[1] + bias[1],
                                acc[2] + bias[2], acc[3] + bias[3]);
        *(float4*)&clsRaw[hw * 400 + nTile * 16 + og * 4] = rv;
    } else {
#pragma unroll
        for (int j = 0; j < 4; j++) {
            int o = (nTile - 25) * 16 + og * 4 + j;
            if (ok[j]) roRaw[hw * 25 + o] = acc[j] + bias[j];
        }
    }
}

// ---------------------------------------------------------------------------
// K2: per-box scores, argmax label, decode, outputs. BYTE-IDENTICAL to the
// R5/R7-verified kernel.
// ---------------------------------------------------------------------------
__global__ __launch_bounds__(256) void k_box(
    const float* __restrict__ clsRaw, const float* __restrict__ roRaw,
    float* __restrict__ out,          // d_out: [32000 bboxes][8000 score][8000 labels][8000 keep]
    float4* __restrict__ nmsBox, float* __restrict__ nmsArea,
    float2* __restrict__ sl)          // packed (score,label) for k_nms scan
{
    const int n = blockIdx.x * 4 + (threadIdx.x >> 6);   // box index 0..7999
    const int lane = threadIdx.x & 63;
    const int hw = n / 5, a = n % 5;

    const float sobj = sigf(roRaw[hw * 25 + a]);
    const float* cbase = clsRaw + hw * 400 + a * 80;

    const int l4 = (lane < 20) ? lane : 19;     // clamp for safe address
    float4 cs = *(const float4*)(cbase + l4 * 4);

    // in-lane first-max over classes l4*4 .. l4*4+3 (strict > keeps first)
    float s0 = sqrtf(sobj * sigf(cs.x));
    float s1 = sqrtf(sobj * sigf(cs.y));
    float s2 = sqrtf(sobj * sigf(cs.z));
    float s3 = sqrtf(sobj * sigf(cs.w));
    float v = s0; int bi = l4 * 4;
    if (s1 > v) { v = s1; bi = l4 * 4 + 1; }
    if (s2 > v) { v = s2; bi = l4 * 4 + 2; }
    if (s3 > v) { v = s3; bi = l4 * 4 + 3; }
    if (lane >= 20) { v = -1.0f; bi = 0x7FFFFFFF; }  // scores are always > 0

    // cross-lane: max score, ties -> lowest class
#pragma unroll
    for (int off = 32; off >= 1; off >>= 1) {
        float ov = __shfl_xor(v, off);
        int   oi = __shfl_xor(bi, off);
        if (ov > v || (ov == v && oi < bi)) { v = ov; bi = oi; }
    }

    if (lane == 0) {
        const float* rp = roRaw + hw * 25 + 5 + a * 4;
        float r0 = rp[0], r1 = rp[1], r2 = rp[2], r3 = rp[3];
        float gx = (float)(hw % FMPX), gy = (float)(hw / FMPX);
        float cx = (sigf(r0) + gx) * 32.0f;
        float cy = (sigf(r1) + gy) * 32.0f;
        float wv = expf(r2) * c_aw[a];
        float hv = expf(r3) * c_ah[a];
        float x1 = cx - wv * 0.5f, y1 = cy - hv * 0.5f;
        float x2 = cx + wv * 0.5f, y2 = cy + hv * 0.5f;

        out[n * 4 + 0] = x1; out[n * 4 + 1] = y1;
        out[n * 4 + 2] = x2; out[n * 4 + 3] = y2;
        out[32000 + n] = v;
        out[40000 + n] = (float)bi;
        out[48000 + n] = 0.0f;            // keep init (k_nms sets 1s later)
        sl[n] = make_float2(v, (float)bi);

        // b2: reinterpret x1y1x2y2 as cxcywh (faithful to the reference nms())
        float nx1 = x1 - x2 * 0.5f, ny1 = y1 - y2 * 0.5f;
        float nx2 = x1 + x2 * 0.5f, ny2 = y1 + y2 * 0.5f;
        nmsBox[n]  = make_float4(nx1, ny1, nx2, ny2);
        nmsArea[n] = (nx2 - nx1) * (ny2 - ny1);
    }
}

// ---------------------------------------------------------------------------
// K3 (R8): same grid/args as R5/R7. R7 post-mortem: per-kept-box shfl_xor
// argmax chain (~23 dependent ds_bpermutes) cost ~750 ns/iter -> 79.6 us.
// Fix: remove ALL cross-lane ops from the greedy loop.
//   Phase 1: scan + LDS-atomic compaction (verbatim R5, proven).
//   Phase 2: rank-sort by counting — thread t's candidate rank = #{j: (s_j,
//     idx_j) before (s_t, idx_t)} via LDS broadcast reads (all threads read
//     the same ss[j] per trip). Ranks unique (strict total order) ->
//     deterministic, == stable argsort(-score). Scatter box+id into sorted
//     LDS arrays. One barrier. Replaces the 36-pass bitonic.
//   Phase 3: wave 0 only. Boxes in registers (4/lane by sorted position);
//     activity = 4 wave-uniform 64-bit __ballot masks (SGPRs). Per position:
//     scalar bit-test (suppressed -> ~5 cyc skip); if kept: 5 uniform LDS
//     broadcast reads of winner box (1 wait), in-register IoU suppression,
//     re-ballot. No shuffles, no barriers, no argmax. Winner needs no
//     explicit retire: ascending k never revisits its bit (self-IoU may
//     clear it; either way correct).
// IoU expression and operand order identical to R5 -> identical keep set.
// ---------------------------------------------------------------------------
__global__ __launch_bounds__(256) void k_nms(
    const float2* __restrict__ sl,
    const float4* __restrict__ nmsBox, const float* __restrict__ nmsArea,
    float* __restrict__ keepOut)
{
    const int c = blockIdx.x;

    __shared__ float ss[CAP];
    __shared__ int   si[CAP];
    __shared__ float rx1[CAP], ry1[CAP], rx2[CAP], ry2[CAP], rar[CAP];
    __shared__ int   rid[CAP];
    __shared__ int   cnt;

    if (threadIdx.x == 0) cnt = 0;
    __syncthreads();

    // ---- phase 1: scan + compact (proven R5 pattern) ----
#pragma unroll 4
    for (int i = threadIdx.x; i < NBOX; i += 256) {
        float2 p = sl[i];
        if (p.x >= 0.3f && (int)p.y == c) {
            int q = atomicAdd(&cnt, 1);          // LDS atomic
            if (q < CAP) { ss[q] = p.x; si[q] = i; }
        }
    }
    __syncthreads();

    int m = cnt;
    if (m > CAP) m = CAP;                        // overflow drop == R5 semantics

    // ---- phase 2: rank-sort by counting + scatter into sorted arrays ----
    {
        const int t = threadIdx.x;
        if (t < m) {
            const float msc = ss[t];
            const int   mid = si[t];
            // issue the global box gather early; latency hides under rank loop
            const float4 b = nmsBox[mid];
            const float  a = nmsArea[mid];
            int rank = 0;
            for (int j = 0; j < m; j++) {        // LDS broadcast reads
                float sj = ss[j]; int ij = si[j];
                if (sj > msc || (sj == msc && ij < mid)) rank++;
            }
            rx1[rank] = b.x; ry1[rank] = b.y;
            rx2[rank] = b.z; ry2[rank] = b.w;
            rar[rank] = a;   rid[rank] = mid;
        }
    }
    __syncthreads();

    // ---- phase 3: ballot-driven greedy, wave 0 only ----
    if (threadIdx.x >= 64) return;
    const int lane = threadIdx.x;

    bool act[4];
    float x1[4], y1[4], x2[4], y2[4], ar[4];
#pragma unroll
    for (int r = 0; r < 4; r++) {
        const int p = r * 64 + lane;             // stride-4B LDS: conflict-free
        act[r] = (p < m);
        if (act[r]) {
            x1[r] = rx1[p]; y1[r] = ry1[p];
            x2[r] = rx2[p]; y2[r] = ry2[p]; ar[r] = rar[p];
        } else {
            x1[r] = 0.f; y1[r] = 0.f; x2[r] = 0.f; y2[r] = 0.f; ar[r] = 0.f;
        }
    }

    unsigned long long M0 = __ballot(act[0]);
    unsigned long long M1 = __ballot(act[1]);
    unsigned long long M2 = __ballot(act[2]);
    unsigned long long M3 = __ballot(act[3]);

    for (int k = 0; k < m; k++) {
        const int w = k >> 6;                    // wave-uniform
        const unsigned long long Mw = (w == 0) ? M0 : (w == 1) ? M1
                                    : (w == 2) ? M2 : M3;
        if (!((Mw >> (k & 63)) & 1ULL)) continue;   // suppressed: scalar skip

        // winner = position k. Uniform LDS broadcast reads (one wait).
        const float kx1 = rx1[k], ky1 = ry1[k];
        const float kx2 = rx2[k], ky2 = ry2[k], ka = rar[k];
        if (lane == 0) keepOut[rid[k]] = 1.0f;

        // suppress every still-active candidate vs winner (all active
        // positions are > k: earlier ones were kept->passed or suppressed)
#pragma unroll
        for (int r = 0; r < 4; r++) {
            if (act[r]) {
                float xx1 = fmaxf(kx1, x1[r]);
                float yy1 = fmaxf(ky1, y1[r]);
                float xx2 = fminf(kx2, x2[r]);
                float yy2 = fminf(ky2, y2[r]);
                float inter = fmaxf(1e-10f, xx2 - xx1) * fmaxf(1e-10f, yy2 - yy1);
                float iou = inter / ((ka + ar[r] - inter) + 1e-14f);
                if (iou > 0.5f) act[r] = false;
            }
        }
        M0 = __ballot(act[0]); M1 = __ballot(act[1]);
        M2 = __ballot(act[2]); M3 = __ballot(act[3]);
    }
}

// ---------------------------------------------------------------------------
extern "C" void kernel_launch(void* const* d_in, const int* in_sizes, int n_in,
                              void* d_out, int out_size, void* d_ws, size_t ws_size,
                              hipStream_t stream) {
    const float* cls_feat = (const float*)d_in[0];
    const float* reg_feat = (const float*)d_in[1];
    const float* w_obj    = (const float*)d_in[2];
    const float* b_obj    = (const float*)d_in[3];
    const float* w_cls    = (const float*)d_in[4];
    const float* b_cls    = (const float*)d_in[5];
    const float* w_reg    = (const float*)d_in[6];
    const float* b_reg    = (const float*)d_in[7];

    float* out = (float*)d_out;
    float* ws  = (float*)d_ws;

    // workspace layout (floats) — IDENTICAL to the R5-proven layout, 2.944 MB
    float*  clsRaw    = ws;                       // 640000
    float*  roRaw     = ws + 640000;              // 40000
    float4* nmsBox    = (float4*)(ws + 680000);   // 32000 floats (16B-aligned offset)
    float*  nmsArea   = ws + 712000;              // 8000
    float2* sl        = (float2*)(ws + 720000);   // 16000 floats (8B-aligned)
    // total 736000 floats

    k_gemm<<<dim3(25, 27), 256, 0, stream>>>(cls_feat, reg_feat,
                                             w_obj, b_obj, w_cls, b_cls, w_reg, b_reg,
                                             clsRaw, roRaw);
    k_box<<<NBOX / 4, 256, 0, stream>>>(clsRaw, roRaw, out, nmsBox, nmsArea, sl);
    k_nms<<<NCLS, 256, 0, stream>>>(sl, nmsBox, nmsArea, out + 48000);
}

// Round 5
// 158.059 us; speedup vs baseline: 1.1893x; 1.0296x over previous
//
#include <hip/hip_runtime.h>
#include <math.h>

#define FMPX 40
#define NPOS 1600          // 40*40
#define NCLS 80
#define NBOX 8000
#define KDIM 512
#define CAP  256           // per-class candidate capacity (expected ~100-200/class)

// anchor (w,h) pairs
__constant__ float c_aw[5] = {17.f, 55.f, 92.f, 202.f, 289.f};
__constant__ float c_ah[5] = {25.f, 75.f, 206.f, 21.f, 311.f};

__device__ __forceinline__ float sigf(float x) { return 1.0f / (1.0f + expf(-x)); }

// ---------------------------------------------------------------------------
// K1: the three 1x1-conv GEMMs. BYTE-IDENTICAL to the R5/R7/R8-verified kernel.
// R3: both A and W in LDS -> LDS-pipe-bound. R4: per-step s_load W worse.
// R5: A straight from GLOBAL (L2-resident), software-pipelined 2x8-k register
// buffers; W staged once into LDS; no barriers in K-loop. FMA order strictly
// sequential ascending k — bitwise-identical across rounds (absmax 2.0).
// ---------------------------------------------------------------------------
__global__ __launch_bounds__(256) void k_gemm(
    const float* __restrict__ cls_feat, const float* __restrict__ reg_feat,
    const float* __restrict__ w_obj, const float* __restrict__ b_obj,
    const float* __restrict__ w_cls, const float* __restrict__ b_cls,
    const float* __restrict__ w_reg, const float* __restrict__ b_reg,
    float* __restrict__ clsRaw,   // [1600][400]
    float* __restrict__ roRaw)    // [1600][25]: 0..4 obj, 5..24 reg
{
    __shared__ float Ws[16 * KDIM];        // 32 KB
    const int mTile = blockIdx.x;          // 0..24
    const int nTile = blockIdx.y;          // 0..26
    const int hw0   = mTile * 64;
    const bool isCls = (nTile < 25);
    const float* feat = isCls ? cls_feat : reg_feat;

    const int pos = threadIdx.x & 63;
    const int og  = threadIdx.x >> 6;      // 0..3 (wave-uniform by construction)

    const float* ap = feat + hw0 + pos;

    float A0[8], A1[8];
#pragma unroll
    for (int t = 0; t < 8; t++) A0[t] = ap[t * NPOS];
#pragma unroll
    for (int t = 0; t < 8; t++) A1[t] = ap[(8 + t) * NPOS];

    for (int i = threadIdx.x * 4; i < 16 * KDIM; i += 256 * 4) {
        int r = i >> 9, k = i & 511;
        const float* src;
        bool valid = true;
        if (isCls) {
            src = w_cls + (nTile * 16 + r) * KDIM + k;
        } else {
            int o = (nTile - 25) * 16 + r;
            if (o < 5)       src = w_obj + o * KDIM + k;
            else if (o < 25) src = w_reg + (o - 5) * KDIM + k;
            else           { src = w_obj; valid = false; }
        }
        float4 v = valid ? *(const float4*)src : make_float4(0.f, 0.f, 0.f, 0.f);
        *(float4*)&Ws[i] = v;
    }

    float bias[4];
    bool ok[4];
#pragma unroll
    for (int j = 0; j < 4; j++) {
        int r = og * 4 + j;
        if (isCls) {
            bias[j] = b_cls[nTile * 16 + r]; ok[j] = true;
        } else {
            int o = (nTile - 25) * 16 + r;
            if (o < 5)       { bias[j] = b_obj[o];     ok[j] = true; }
            else if (o < 25) { bias[j] = b_reg[o - 5]; ok[j] = true; }
            else             { bias[j] = 0.0f;         ok[j] = false; }
        }
    }

    __syncthreads();   // Ws ready; only barrier in the kernel

    float acc[4] = {0.f, 0.f, 0.f, 0.f};
    const float* wsBase = &Ws[(og * 4) * KDIM];

    for (int kk = 0; kk < KDIM - 16; kk += 16) {
#pragma unroll
        for (int j = 0; j < 4; j++) {
            const float* wp = wsBase + j * KDIM + kk;
            acc[j] += A0[0] * wp[0]; acc[j] += A0[1] * wp[1];
            acc[j] += A0[2] * wp[2]; acc[j] += A0[3] * wp[3];
            acc[j] += A0[4] * wp[4]; acc[j] += A0[5] * wp[5];
            acc[j] += A0[6] * wp[6]; acc[j] += A0[7] * wp[7];
        }
#pragma unroll
        for (int t = 0; t < 8; t++) A0[t] = ap[(kk + 16 + t) * NPOS];
#pragma unroll
        for (int j = 0; j < 4; j++) {
            const float* wp = wsBase + j * KDIM + kk + 8;
            acc[j] += A1[0] * wp[0]; acc[j] += A1[1] * wp[1];
            acc[j] += A1[2] * wp[2]; acc[j] += A1[3] * wp[3];
            acc[j] += A1[4] * wp[4]; acc[j] += A1[5] * wp[5];
            acc[j] += A1[6] * wp[6]; acc[j] += A1[7] * wp[7];
        }
#pragma unroll
        for (int t = 0; t < 8; t++) A1[t] = ap[(kk + 24 + t) * NPOS];
    }
    {
        const int kk = KDIM - 16;
#pragma unroll
        for (int j = 0; j < 4; j++) {
            const float* wp = wsBase + j * KDIM + kk;
            acc[j] += A0[0] * wp[0]; acc[j] += A0[1] * wp[1];
            acc[j] += A0[2] * wp[2]; acc[j] += A0[3] * wp[3];
            acc[j] += A0[4] * wp[4]; acc[j] += A0[5] * wp[5];
            acc[j] += A0[6] * wp[6]; acc[j] += A0[7] * wp[7];
        }
#pragma unroll
        for (int j = 0; j < 4; j++) {
            const float* wp = wsBase + j * KDIM + kk + 8;
            acc[j] += A1[0] * wp[0]; acc[j] += A1[1] * wp[1];
            acc[j] += A1[2] * wp[2]; acc[j] += A1[3] * wp[3];
            acc[j] += A1[4] * wp[4]; acc[j] += A1[5] * wp[5];
            acc[j] += A1[6] * wp[6]; acc[j] += A1[7] * wp[7];
        }
    }

    const int hw = hw0 + pos;
    if (isCls) {
        float4 rv = make_float4(acc[0] + bias[0], acc[1] + bias[1],
                                acc[2] + bias[2], acc[3] + bias[3]);
        *(float4*)&clsRaw[hw * 400 + nTile * 16 + og * 4] = rv;
    } else {
#pragma unroll
        for (int j = 0; j < 4; j++) {
            int o = (nTile - 25) * 16 + og * 4 + j;
            if (ok[j]) roRaw[hw * 25 + o] = acc[j] + bias[j];
        }
    }
}

// ---------------------------------------------------------------------------
// K2: per-box scores, argmax label, decode, outputs. BYTE-IDENTICAL to the
// R5/R7/R8-verified kernel.
// ---------------------------------------------------------------------------
__global__ __launch_bounds__(256) void k_box(
    const float* __restrict__ clsRaw, const float* __restrict__ roRaw,
    float* __restrict__ out,          // d_out: [32000 bboxes][8000 score][8000 labels][8000 keep]
    float4* __restrict__ nmsBox, float* __restrict__ nmsArea,
    float2* __restrict__ sl)          // packed (score,label) for k_nms scan
{
    const int n = blockIdx.x * 4 + (threadIdx.x >> 6);   // box index 0..7999
    const int lane = threadIdx.x & 63;
    const int hw = n / 5, a = n % 5;

    const float sobj = sigf(roRaw[hw * 25 + a]);
    const float* cbase = clsRaw + hw * 400 + a * 80;

    const int l4 = (lane < 20) ? lane : 19;     // clamp for safe address
    float4 cs = *(const float4*)(cbase + l4 * 4);

    float s0 = sqrtf(sobj * sigf(cs.x));
    float s1 = sqrtf(sobj * sigf(cs.y));
    float s2 = sqrtf(sobj * sigf(cs.z));
    float s3 = sqrtf(sobj * sigf(cs.w));
    float v = s0; int bi = l4 * 4;
    if (s1 > v) { v = s1; bi = l4 * 4 + 1; }
    if (s2 > v) { v = s2; bi = l4 * 4 + 2; }
    if (s3 > v) { v = s3; bi = l4 * 4 + 3; }
    if (lane >= 20) { v = -1.0f; bi = 0x7FFFFFFF; }  // scores are always > 0

#pragma unroll
    for (int off = 32; off >= 1; off >>= 1) {
        float ov = __shfl_xor(v, off);
        int   oi = __shfl_xor(bi, off);
        if (ov > v || (ov == v && oi < bi)) { v = ov; bi = oi; }
    }

    if (lane == 0) {
        const float* rp = roRaw + hw * 25 + 5 + a * 4;
        float r0 = rp[0], r1 = rp[1], r2 = rp[2], r3 = rp[3];
        float gx = (float)(hw % FMPX), gy = (float)(hw / FMPX);
        float cx = (sigf(r0) + gx) * 32.0f;
        float cy = (sigf(r1) + gy) * 32.0f;
        float wv = expf(r2) * c_aw[a];
        float hv = expf(r3) * c_ah[a];
        float x1 = cx - wv * 0.5f, y1 = cy - hv * 0.5f;
        float x2 = cx + wv * 0.5f, y2 = cy + hv * 0.5f;

        out[n * 4 + 0] = x1; out[n * 4 + 1] = y1;
        out[n * 4 + 2] = x2; out[n * 4 + 3] = y2;
        out[32000 + n] = v;
        out[40000 + n] = (float)bi;
        out[48000 + n] = 0.0f;            // keep init (k_nms sets 1s later)
        sl[n] = make_float2(v, (float)bi);

        // b2: reinterpret x1y1x2y2 as cxcywh (faithful to the reference nms())
        float nx1 = x1 - x2 * 0.5f, ny1 = y1 - y2 * 0.5f;
        float nx2 = x1 + x2 * 0.5f, ny2 = y1 + y2 * 0.5f;
        nmsBox[n]  = make_float4(nx1, ny1, nx2, ny2);
        nmsArea[n] = (nx2 - nx1) * (ny2 - ny1);
    }
}

// ---------------------------------------------------------------------------
// K3 (R9): R8 post-mortem — the per-kept-box serial chain still held the IoU
// math (4 IEEE divisions, ~200+ cyc) + LDS box reads + 4 re-ballots (~500+
// cyc/iter). Fix: hoist ALL pairwise IoU into a fully parallel edge-matrix
// phase; the serial loop becomes mask-only.
//   Phase 1: scan + LDS-atomic compaction (verbatim R5/R8, proven).
//   Phase 2: rank-sort by counting (proven R8 logic); scatter float4 box +
//     area + id into sorted LDS arrays.
//   Phase 2.5 (parallel): thread p computes edge row p: bit j set iff
//     iou(p,j) > 0.5 (IDENTICAL IoU expression; fmax/add bitwise-symmetric
//     for finite operands -> edge(p,j) == reference iou[k,j] test either
//     direction). Stored word-major erow[4][CAP] (2-way bank alias = free).
//     Self-bit always set (iou_self = a/(a+1e-14) > 0.5; area >= ~0.2).
//   Phase 3 (serial, minimal): wave 0; ALIVE = 4 x u64 in registers.
//     Per KEPT box only: ctz-scan -> 4 uniform LDS row reads + rid (the one
//     ~140 cyc wait) -> A &= ~row (self-bit retires winner; static-unrolled
//     explicit self-clear as insurance) -> lane-0 store. No divisions, no
//     ballots, no skipped iterations. ff1-ascending == sorted-order greedy
//     (an alive j < k is impossible: ff1 would have returned it first).
// All local arrays statically indexed (rule #20: e/A dynamic-index avoided
// via compile-time-w unrolled loops).
// ---------------------------------------------------------------------------
__global__ __launch_bounds__(256) void k_nms(
    const float2* __restrict__ sl,
    const float4* __restrict__ nmsBox, const float* __restrict__ nmsArea,
    float* __restrict__ keepOut)
{
    const int c = blockIdx.x;

    __shared__ float  ss[CAP];
    __shared__ int    si[CAP];
    __shared__ float4 sb4[CAP];                       // sorted boxes
    __shared__ float  sar[CAP];                       // sorted areas
    __shared__ int    rid[CAP];                       // sorted original ids
    __shared__ unsigned long long erow[4][CAP];       // edge rows, word-major
    __shared__ int    cnt;

    if (threadIdx.x == 0) cnt = 0;
    __syncthreads();

    // ---- phase 1: scan + compact (proven) ----
#pragma unroll 4
    for (int i = threadIdx.x; i < NBOX; i += 256) {
        float2 p = sl[i];
        if (p.x >= 0.3f && (int)p.y == c) {
            int q = atomicAdd(&cnt, 1);          // LDS atomic
            if (q < CAP) { ss[q] = p.x; si[q] = i; }
        }
    }
    __syncthreads();

    int m = cnt;
    if (m > CAP) m = CAP;                        // overflow drop == R5 semantics

    // ---- phase 2: rank-sort by counting + scatter into sorted arrays ----
    {
        const int t = threadIdx.x;
        if (t < m) {
            const float msc = ss[t];
            const int   mid = si[t];
            // issue global gathers early; latency hides under the rank loop
            const float4 b = nmsBox[mid];
            const float  a = nmsArea[mid];
            int rank = 0;
            for (int j = 0; j < m; j++) {        // LDS broadcast reads
                float sj = ss[j]; int ij = si[j];
                if (sj > msc || (sj == msc && ij < mid)) rank++;
            }
            sb4[rank] = b; sar[rank] = a; rid[rank] = mid;
        }
    }
    __syncthreads();

    // ---- phase 2.5: parallel edge-matrix build ----
    {
        const int p = threadIdx.x;
        if (p < m) {
            const float4 pb = sb4[p];
            const float  pa = sar[p];
#pragma unroll
            for (int w = 0; w < 4; w++) {        // compile-time w (rule #20)
                unsigned long long ew = 0ull;
                const int j0 = w * 64;
                const int j1 = (m < j0 + 64) ? m : (j0 + 64);
                for (int j = j0; j < j1; j++) {
                    float4 bj = sb4[j];          // broadcast b128
                    float  aj = sar[j];
                    float xx1 = fmaxf(pb.x, bj.x);
                    float yy1 = fmaxf(pb.y, bj.y);
                    float xx2 = fminf(pb.z, bj.z);
                    float yy2 = fminf(pb.w, bj.w);
                    float inter = fmaxf(1e-10f, xx2 - xx1) * fmaxf(1e-10f, yy2 - yy1);
                    float iou = inter / ((pa + aj - inter) + 1e-14f);
                    if (iou > 0.5f) ew |= (1ull << (j & 63));
                }
                erow[w][p] = ew;
            }
        }
    }
    __syncthreads();

    // ---- phase 3: mask-only serial resolution, wave 0 ----
    if (threadIdx.x >= 64) return;
    const int lane = threadIdx.x;

    unsigned long long A[4];
#pragma unroll
    for (int w = 0; w < 4; w++) {
        int lo = w * 64;
        A[w] = (m >= lo + 64) ? ~0ull
             : (m > lo ? ((1ull << (m - lo)) - 1ull) : 0ull);
    }

    for (int guard = 0; guard < m; guard++) {
        int k = -1;
#pragma unroll
        for (int w = 0; w < 4; w++)
            if (k < 0 && A[w] != 0ull) k = w * 64 + (int)__builtin_ctzll(A[w]);
        if (k < 0) break;

        // the only memory wait in the loop: row + id, uniform broadcast reads
        unsigned long long r0 = erow[0][k];
        unsigned long long r1 = erow[1][k];
        unsigned long long r2 = erow[2][k];
        unsigned long long r3 = erow[3][k];
        int kid = rid[k];
        if (lane == 0) keepOut[kid] = 1.0f;

#pragma unroll
        for (int w = 0; w < 4; w++)              // static-index self-clear
            if ((k >> 6) == w) A[w] &= ~(1ull << (k & 63));
        A[0] &= ~r0; A[1] &= ~r1; A[2] &= ~r2; A[3] &= ~r3;
    }
}

// ---------------------------------------------------------------------------
extern "C" void kernel_launch(void* const* d_in, const int* in_sizes, int n_in,
                              void* d_out, int out_size, void* d_ws, size_t ws_size,
                              hipStream_t stream) {
    const float* cls_feat = (const float*)d_in[0];
    const float* reg_feat = (const float*)d_in[1];
    const float* w_obj    = (const float*)d_in[2];
    const float* b_obj    = (const float*)d_in[3];
    const float* w_cls    = (const float*)d_in[4];
    const float* b_cls    = (const float*)d_in[5];
    const float* w_reg    = (const float*)d_in[6];
    const float* b_reg    = (const float*)d_in[7];

    float* out = (float*)d_out;
    float* ws  = (float*)d_ws;

    // workspace layout (floats) — IDENTICAL to the R5-proven layout, 2.944 MB
    float*  clsRaw    = ws;                       // 640000
    float*  roRaw     = ws + 640000;              // 40000
    float4* nmsBox    = (float4*)(ws + 680000);   // 32000 floats (16B-aligned offset)
    float*  nmsArea   = ws + 712000;              // 8000
    float2* sl        = (float2*)(ws + 720000);   // 16000 floats (8B-aligned)
    // total 736000 floats

    k_gemm<<<dim3(25, 27), 256, 0, stream>>>(cls_feat, reg_feat,
                                             w_obj, b_obj, w_cls, b_cls, w_reg, b_reg,
                                             clsRaw, roRaw);
    k_box<<<NBOX / 4, 256, 0, stream>>>(clsRaw, roRaw, out, nmsBox, nmsArea, sl);
    k_nms<<<NCLS, 256, 0, stream>>>(sl, nmsBox, nmsArea, out + 48000);
}